// Round 18
// baseline (182.706 us; speedup 1.0000x reference)
//
#include <hip/hip_runtime.h>
#include <hip/hip_fp16.h>

#define NFEAT 512
#define HID 16
#define MAXNB 512          // max buckets (N/256 = 391 for N=100K)
#define NBLK 512           // hist/scatter blocks within merged kernels
#define PACK_SHIFT 17      // src fits in 17 bits (N < 131072)
#define PACK_MASK ((1 << PACK_SHIFT) - 1)

typedef _Float16 f16x8 __attribute__((ext_vector_type(8)));
typedef float f32x4 __attribute__((ext_vector_type(4)));

// ---- shared device helper: one 16x16 MFMA tile of x@W1 (unscaled, fp16 out) ----
__device__ __forceinline__ void gemm_tile(const float* __restrict__ x,
                                          const float* __restrict__ W,
                                          __half* __restrict__ h1u,
                                          int tile, int N, int lane) {
  const int n = lane & 15;
  const int g = lane >> 4;

  f16x8 bf[16];
#pragma unroll
  for (int f = 0; f < 16; ++f) {
    const float* wp = W + (size_t)(f * 32 + g * 8) * HID + n;
#pragma unroll
    for (int j = 0; j < 8; ++j) bf[f][j] = (_Float16)wp[j * HID];
  }

  int rowbase = tile * 16;
  if (rowbase + 16 > N) rowbase = N - 16;  // overlap-safe: rewrites same values
  const float* xr = x + (size_t)(rowbase + n) * NFEAT + g * 8;

  f32x4 acc = {0.f, 0.f, 0.f, 0.f};
#pragma unroll
  for (int f = 0; f < 16; ++f) {
    float4 p0 = *(const float4*)(xr + f * 32);
    float4 p1 = *(const float4*)(xr + f * 32 + 4);
    f16x8 af;
    af[0] = (_Float16)p0.x; af[1] = (_Float16)p0.y;
    af[2] = (_Float16)p0.z; af[3] = (_Float16)p0.w;
    af[4] = (_Float16)p1.x; af[5] = (_Float16)p1.y;
    af[6] = (_Float16)p1.z; af[7] = (_Float16)p1.w;
    acc = __builtin_amdgcn_mfma_f32_16x16x32_f16(af, bf[f], acc, 0, 0, 0);
  }

#pragma unroll
  for (int r = 0; r < 4; ++r) {
    int row = rowbase + g * 4 + r;
    h1u[(size_t)row * HID + n] = __float2half(acc[r]);
  }
}

// ============ K1: hist2d (blocks < NBLK)  ||  gemm tiles [0, t1) ============
__global__ __launch_bounds__(512) void k_hist_gemm(const int* __restrict__ ei,
                                                   int* __restrict__ cnt_t,
                                                   int E, int nb,
                                                   const float* __restrict__ x,
                                                   const float* __restrict__ W,
                                                   __half* __restrict__ h1u,
                                                   int N, int t1) {
  __shared__ int l[MAXNB];
  if (blockIdx.x < NBLK) {
    for (int i = threadIdx.x; i < nb; i += 512) l[i] = 0;
    __syncthreads();
    int chunk = (E + NBLK - 1) / NBLK;
    int beg = blockIdx.x * chunk;
    int end = beg + chunk; if (end > E) end = E;
    for (int e = beg + threadIdx.x; e < end; e += 512)
      atomicAdd(&l[ei[(size_t)E + e] >> 8], 1);
    __syncthreads();
    for (int b = threadIdx.x; b < nb; b += 512)
      cnt_t[(size_t)b * NBLK + blockIdx.x] = l[b];
  } else {
    int tile = (blockIdx.x - NBLK) * 8 + (threadIdx.x >> 6);
    if (tile < t1) gemm_tile(x, W, h1u, tile, N, threadIdx.x & 63);
  }
}

// ========= K2: per-bucket column scan (wave per bucket; off_t + gcnt) =========
__global__ __launch_bounds__(512) void k_scan(const int* __restrict__ cnt_t,
                                              int* __restrict__ off_t,
                                              int* __restrict__ gcnt, int nb) {
  int b = blockIdx.x * 8 + (threadIdx.x >> 6);
  if (b >= nb) return;
  int lane = threadIdx.x & 63;
  int4 v0 = *(const int4*)&cnt_t[(size_t)b * NBLK + lane * 8];
  int4 v1 = *(const int4*)&cnt_t[(size_t)b * NBLK + lane * 8 + 4];
  int tot = (v0.x + v0.y + v0.z + v0.w) + (v1.x + v1.y + v1.z + v1.w);
  int s = tot;
  for (int d = 1; d < 64; d <<= 1) {
    int o = __shfl_up(s, d);
    if (lane >= d) s += o;
  }
  int excl = s - tot;
  int4 w0, w1;
  w0.x = excl;
  w0.y = w0.x + v0.x;
  w0.z = w0.y + v0.y;
  w0.w = w0.z + v0.z;
  w1.x = w0.w + v0.w;
  w1.y = w1.x + v1.x;
  w1.z = w1.y + v1.y;
  w1.w = w1.z + v1.z;
  *(int4*)&off_t[(size_t)b * NBLK + lane * 8] = w0;
  *(int4*)&off_t[(size_t)b * NBLK + lane * 8 + 4] = w1;
  if (lane == 63) gcnt[b] = s;
}

// inline 512-wide exclusive scan of padded gcnt -> sm holds inclusive padded sums
__device__ __forceinline__ void bscan_lds(const int* __restrict__ gcnt, int nb,
                                          int* sm /*LDS[512]*/, int& my_pc) {
  int t = threadIdx.x;
  int c = (t < nb) ? gcnt[t] : 0;
  my_pc = (c + 15) & ~15;
  sm[t] = my_pc;
  __syncthreads();
  for (int off = 1; off < 512; off <<= 1) {
    int x = (t >= off) ? sm[t - off] : 0;
    __syncthreads();
    sm[t] += x;
    __syncthreads();
  }
}

// ====== K3: scatter (blocks < NBLK, inline base-scan)  ||  gemm [t1, t2) ======
__global__ __launch_bounds__(512) void k_scatter_gemm(const int* __restrict__ ei,
                                                      const int* __restrict__ gcnt,
                                                      const int* __restrict__ off_t,
                                                      int* __restrict__ binned,
                                                      int E, int nb,
                                                      const float* __restrict__ x,
                                                      const float* __restrict__ W,
                                                      __half* __restrict__ h1u,
                                                      int N, int t1, int t2) {
  __shared__ int cur[MAXNB];
  __shared__ int sm[512];
  if (blockIdx.x < NBLK) {
    int my_pc;
    bscan_lds(gcnt, nb, sm, my_pc);
    int t = threadIdx.x;
    if (t < nb) cur[t] = (sm[t] - my_pc) + off_t[(size_t)t * NBLK + blockIdx.x];
    __syncthreads();
    int chunk = (E + NBLK - 1) / NBLK;
    int beg = blockIdx.x * chunk;
    int end = beg + chunk; if (end > E) end = E;
    for (int e = beg + threadIdx.x; e < end; e += 512) {
      int s = ei[e];
      int d = ei[(size_t)E + e];
      int b = d >> 8;
      int pos = atomicAdd(&cur[b], 1);
      binned[pos] = s | ((d & 255) << PACK_SHIFT);
    }
  } else {
    int tile = t1 + (blockIdx.x - NBLK) * 8 + (threadIdx.x >> 6);
    if (tile < t2) gemm_tile(x, W, h1u, tile, N, threadIdx.x & 63);
  }
}

// ====== K4: per-bucket sort -> CSR + dinv (blocks < nb)  ||  gemm [t2, ntiles) ======
__global__ __launch_bounds__(512) void k_sort_gemm(const int* __restrict__ gcnt,
                                                   const int* __restrict__ binned,
                                                   int* __restrict__ csr,
                                                   int* __restrict__ rowbeg,
                                                   int* __restrict__ rowend,
                                                   float* __restrict__ dinv,
                                                   int nb, int N,
                                                   const float* __restrict__ x,
                                                   const float* __restrict__ W,
                                                   __half* __restrict__ h1u,
                                                   int t2, int ntiles) {
  __shared__ int smg[512];
  __shared__ int hist[256];
  __shared__ int sm[256];
  __shared__ int cur[256];
  __shared__ int sbase;
  const int t = threadIdx.x;
  const int b = blockIdx.x;
  if (b >= nb) {
    int tile = t2 + (b - nb) * 8 + (t >> 6);
    if (tile < ntiles) gemm_tile(x, W, h1u, tile, N, t & 63);
    return;
  }
  // inline base scan for this bucket
  {
    int my_pc;
    bscan_lds(gcnt, nb, smg, my_pc);
    if (t == b) sbase = smg[t] - my_pc;  // thread b holds bucket b's entry
    __syncthreads();
  }
  const int base = sbase;
  const int cnt = gcnt[b];
  if (t < 256) hist[t] = 0;
  __syncthreads();
  for (int j = base + t; j < base + cnt; j += 512)
    atomicAdd(&hist[binned[j] >> PACK_SHIFT], 1);
  __syncthreads();
  int h = 0;
  if (t < 256) {
    h = hist[t];
    sm[t] = h;
  }
  __syncthreads();
  for (int off = 1; off < 256; off <<= 1) {
    int x2 = 0;
    if (t < 256 && t >= off) x2 = sm[t - off];
    __syncthreads();
    if (t < 256) sm[t] += x2;
    __syncthreads();
  }
  if (t < 256) {
    int incl = sm[t];
    int excl = incl - h;
    cur[t] = excl;
    int node = b * 256 + t;
    if (node < N) {
      rowbeg[node] = base + excl;
      rowend[node] = base + incl;
      dinv[node] = rsqrtf((float)h + 1.0f);
    }
  }
  __syncthreads();
  for (int j = base + t; j < base + cnt; j += 512) {
    int val = binned[j];
    int pos = atomicAdd(&cur[val >> PACK_SHIFT], 1);
    csr[base + pos] = val & PACK_MASK;
  }
}

// ===== layer1 agg + relu + W2. 16 lanes/node; dinv[src] applied at gather. =====
__global__ __launch_bounds__(256) void k_agg1f(const int* __restrict__ rowbeg,
                                               const int* __restrict__ rowend,
                                               const int* __restrict__ csr,
                                               const __half* __restrict__ h1u,
                                               const float* __restrict__ dinv,
                                               const float* __restrict__ b1,
                                               const float* __restrict__ W2,
                                               float* __restrict__ h2s, int N) {
  const int f = threadIdx.x & 15;
  const int node = blockIdx.x * 16 + (threadIdx.x >> 4);
  if (node >= N) return;
  int j = rowbeg[node];
  const int end = rowend[node];
  const float di = dinv[node];
  float acc = __half2float(h1u[(size_t)node * HID + f]) * di;  // self loop
  for (; j < end && (j & 3); ++j) {
    int s = csr[j];
    acc += __half2float(h1u[(size_t)s * HID + f]) * dinv[s];
  }
  for (; j + 8 <= end; j += 8) {
    int4 s0 = *(const int4*)&csr[j];
    int4 s1 = *(const int4*)&csr[j + 4];
    float d0 = dinv[s0.x], d1 = dinv[s0.y], d2 = dinv[s0.z], d3 = dinv[s0.w];
    float d4 = dinv[s1.x], d5 = dinv[s1.y], d6 = dinv[s1.z], d7 = dinv[s1.w];
    float a0 = __half2float(h1u[(size_t)s0.x * HID + f]) * d0;
    float a1 = __half2float(h1u[(size_t)s0.y * HID + f]) * d1;
    float a2 = __half2float(h1u[(size_t)s0.z * HID + f]) * d2;
    float a3 = __half2float(h1u[(size_t)s0.w * HID + f]) * d3;
    float a4 = __half2float(h1u[(size_t)s1.x * HID + f]) * d4;
    float a5 = __half2float(h1u[(size_t)s1.y * HID + f]) * d5;
    float a6 = __half2float(h1u[(size_t)s1.z * HID + f]) * d6;
    float a7 = __half2float(h1u[(size_t)s1.w * HID + f]) * d7;
    acc += ((a0 + a1) + (a2 + a3)) + ((a4 + a5) + (a6 + a7));
  }
  for (; j + 4 <= end; j += 4) {
    int4 ss = *(const int4*)&csr[j];
    float a0 = __half2float(h1u[(size_t)ss.x * HID + f]) * dinv[ss.x];
    float a1 = __half2float(h1u[(size_t)ss.y * HID + f]) * dinv[ss.y];
    float a2 = __half2float(h1u[(size_t)ss.z * HID + f]) * dinv[ss.z];
    float a3 = __half2float(h1u[(size_t)ss.w * HID + f]) * dinv[ss.w];
    acc += (a0 + a1) + (a2 + a3);
  }
  for (; j < end; ++j) {
    int s = csr[j];
    acc += __half2float(h1u[(size_t)s * HID + f]) * dinv[s];
  }

  float v = fmaxf(acc * di + b1[f], 0.f);
  float o0 = v * W2[f * 2 + 0];
  float o1 = v * W2[f * 2 + 1];
#pragma unroll
  for (int d = 1; d < 16; d <<= 1) {
    o0 += __shfl_xor(o0, d);
    o1 += __shfl_xor(o1, d);
  }
  if (f == 0) *(float2*)&h2s[(size_t)node * 2] = make_float2(o0 * di, o1 * di);
}

// ===== layer2 aggregation + bias. 4 lanes per node (24 waves/CU). =====
__global__ __launch_bounds__(256) void k_agg2f(const int* __restrict__ rowbeg,
                                               const int* __restrict__ rowend,
                                               const int* __restrict__ csr,
                                               const float* __restrict__ h2s,
                                               const float* __restrict__ dinv,
                                               const float* __restrict__ b2,
                                               float* __restrict__ out, int N) {
  const int l = threadIdx.x & 3;
  const int node = blockIdx.x * 64 + (threadIdx.x >> 2);
  if (node >= N) return;
  const int beg = rowbeg[node];
  const int end = rowend[node];
  float ox = 0.f, oy = 0.f;
  for (int j = beg + l; j < end; j += 4) {
    int s = csr[j];
    float2 v = *(const float2*)&h2s[(size_t)s * 2];
    ox += v.x;
    oy += v.y;
  }
  ox += __shfl_xor(ox, 1); oy += __shfl_xor(oy, 1);
  ox += __shfl_xor(ox, 2); oy += __shfl_xor(oy, 2);
  if (l == 0) {
    float2 self = *(const float2*)&h2s[(size_t)node * 2];
    float di = dinv[node];
    float2 o;
    o.x = (ox + self.x) * di + b2[0];
    o.y = (oy + self.y) * di + b2[1];
    *(float2*)&out[(size_t)node * 2] = o;
  }
}

// ================= launch =================
extern "C" void kernel_launch(void* const* d_in, const int* in_sizes, int n_in,
                              void* d_out, int out_size, void* d_ws, size_t ws_size,
                              hipStream_t stream) {
  const float* x = (const float*)d_in[0];
  const int* ei = (const int*)d_in[1];  // harness delivers integer inputs as int32
  const float* W1 = (const float*)d_in[2];
  const float* b1 = (const float*)d_in[3];
  const float* W2 = (const float*)d_in[4];
  const float* b2 = (const float*)d_in[5];
  float* out = (float*)d_out;
  const int N = in_sizes[0] / NFEAT;
  const int E = in_sizes[1] / 2;
  const int nb = (N + 255) / 256;  // buckets of 256 nodes

  char* p = (char*)d_ws;
  int* cnt_t = (int*)p;    p += (size_t)MAXNB * NBLK * 4;
  int* off_t = (int*)p;    p += (size_t)MAXNB * NBLK * 4;
  int* gcnt = (int*)p;     p += (size_t)MAXNB * 4;
  int* binned = (int*)p;   p += ((size_t)E + MAXNB * 16) * 4;
  int* csr = (int*)p;      p += ((size_t)E + MAXNB * 16) * 4;
  int* rowbeg = (int*)p;   p += (size_t)N * 4;
  int* rowend = (int*)p;   p += (size_t)N * 4;
  float* dinv = (float*)p; p += (size_t)N * 4;
  __half* h1u = (__half*)p; p += (size_t)N * HID * 2;
  float* h2s = (float*)p;  p += (size_t)N * 2 * 4;

  const int ntiles = (N + 15) / 16;
  const int t1 = ((ntiles / 3) + 7) & ~7;                // thirds, x8 aligned
  const int t2 = ((2 * ntiles / 3) + 7) & ~7;
  const int gA = (t1 + 7) / 8;
  const int gB = (t2 - t1 + 7) / 8;
  const int gC = (ntiles - t2 + 7) / 8;

  k_hist_gemm<<<NBLK + gA, 512, 0, stream>>>(ei, cnt_t, E, nb, x, W1, h1u, N, t1);
  k_scan<<<(nb + 7) / 8, 512, 0, stream>>>(cnt_t, off_t, gcnt, nb);
  k_scatter_gemm<<<NBLK + gB, 512, 0, stream>>>(ei, gcnt, off_t, binned, E, nb,
                                                x, W1, h1u, N, t1, t2);
  k_sort_gemm<<<nb + gC, 512, 0, stream>>>(gcnt, binned, csr, rowbeg, rowend,
                                           dinv, nb, N, x, W1, h1u, t2, ntiles);
  k_agg1f<<<(N + 15) / 16, 256, 0, stream>>>(rowbeg, rowend, csr, h1u, dinv, b1, W2, h2s, N);
  k_agg2f<<<(N + 63) / 64, 256, 0, stream>>>(rowbeg, rowend, csr, h2s, dinv, b2, out, N);
}

// Round 19
// 166.308 us; speedup vs baseline: 1.0986x; 1.0986x over previous
//
#include <hip/hip_runtime.h>
#include <hip/hip_fp16.h>

#define NFEAT 512
#define HID 16
#define MAXNB 512          // max buckets (N/256 = 391 for N=100K)
#define NBLK 512           // hist/scatter blocks within merged kernels
#define PACK_SHIFT 17      // src fits in 17 bits (N < 131072)
#define PACK_MASK ((1 << PACK_SHIFT) - 1)

typedef _Float16 f16x8 __attribute__((ext_vector_type(8)));
typedef float f32x4 __attribute__((ext_vector_type(4)));

// ---- shared device helper: one 16x16 MFMA tile of x@W1 (unscaled, fp16 out) ----
__device__ __forceinline__ void gemm_tile(const float* __restrict__ x,
                                          const float* __restrict__ W,
                                          __half* __restrict__ h1u,
                                          int tile, int N, int lane) {
  const int n = lane & 15;
  const int g = lane >> 4;

  f16x8 bf[16];
#pragma unroll
  for (int f = 0; f < 16; ++f) {
    const float* wp = W + (size_t)(f * 32 + g * 8) * HID + n;
#pragma unroll
    for (int j = 0; j < 8; ++j) bf[f][j] = (_Float16)wp[j * HID];
  }

  int rowbase = tile * 16;
  if (rowbase + 16 > N) rowbase = N - 16;  // overlap-safe: rewrites same values
  const float* xr = x + (size_t)(rowbase + n) * NFEAT + g * 8;

  f32x4 acc = {0.f, 0.f, 0.f, 0.f};
#pragma unroll
  for (int f = 0; f < 16; ++f) {
    float4 p0 = *(const float4*)(xr + f * 32);
    float4 p1 = *(const float4*)(xr + f * 32 + 4);
    f16x8 af;
    af[0] = (_Float16)p0.x; af[1] = (_Float16)p0.y;
    af[2] = (_Float16)p0.z; af[3] = (_Float16)p0.w;
    af[4] = (_Float16)p1.x; af[5] = (_Float16)p1.y;
    af[6] = (_Float16)p1.z; af[7] = (_Float16)p1.w;
    acc = __builtin_amdgcn_mfma_f32_16x16x32_f16(af, bf[f], acc, 0, 0, 0);
  }

#pragma unroll
  for (int r = 0; r < 4; ++r) {
    int row = rowbase + g * 4 + r;
    h1u[(size_t)row * HID + n] = __float2half(acc[r]);
  }
}

// ==== K1: hist2d w/ dual sub-histogram (blocks < NBLK) || gemm tiles [0, tsplit) ====
__global__ __launch_bounds__(512) void k_hist_gemm(const int* __restrict__ ei,
                                                   int* __restrict__ cnt_t,
                                                   int E, int nb,
                                                   const float* __restrict__ x,
                                                   const float* __restrict__ W,
                                                   __half* __restrict__ h1u,
                                                   int N, int tsplit) {
  __shared__ int l[2][MAXNB];
  if (blockIdx.x < NBLK) {
    for (int i = threadIdx.x; i < nb; i += 512) {
      l[0][i] = 0;
      l[1][i] = 0;
    }
    __syncthreads();
    const int par = threadIdx.x & 1;
    int chunk = (E + NBLK - 1) / NBLK;
    int beg = blockIdx.x * chunk;
    int end = beg + chunk; if (end > E) end = E;
    for (int e = beg + threadIdx.x; e < end; e += 512)
      atomicAdd(&l[par][ei[(size_t)E + e] >> 8], 1);
    __syncthreads();
    for (int b = threadIdx.x; b < nb; b += 512)
      cnt_t[(size_t)b * NBLK + blockIdx.x] = l[0][b] + l[1][b];
  } else {
    int tile = (blockIdx.x - NBLK) * 8 + (threadIdx.x >> 6);
    if (tile < tsplit) gemm_tile(x, W, h1u, tile, N, threadIdx.x & 63);
  }
}

// ============ per-bucket column scan (one wave per bucket, 8 counts/lane) ====
__global__ __launch_bounds__(64) void k_colscan(const int* __restrict__ cnt_t,
                                                int* __restrict__ off_t,
                                                int* __restrict__ gcnt, int nb) {
  int b = blockIdx.x;
  if (b >= nb) return;
  int lane = threadIdx.x;
  int4 v0 = *(const int4*)&cnt_t[(size_t)b * NBLK + lane * 8];
  int4 v1 = *(const int4*)&cnt_t[(size_t)b * NBLK + lane * 8 + 4];
  int tot = (v0.x + v0.y + v0.z + v0.w) + (v1.x + v1.y + v1.z + v1.w);
  int s = tot;
  for (int d = 1; d < 64; d <<= 1) {
    int o = __shfl_up(s, d);
    if (lane >= d) s += o;
  }
  int excl = s - tot;
  int4 w0, w1;
  w0.x = excl;
  w0.y = w0.x + v0.x;
  w0.z = w0.y + v0.y;
  w0.w = w0.z + v0.z;
  w1.x = w0.w + v0.w;
  w1.y = w1.x + v1.x;
  w1.z = w1.y + v1.y;
  w1.w = w1.z + v1.z;
  *(int4*)&off_t[(size_t)b * NBLK + lane * 8] = w0;
  *(int4*)&off_t[(size_t)b * NBLK + lane * 8 + 4] = w1;
  if (lane == 63) gcnt[b] = s;
}

// ============ scan: 16-aligned bucket bases ============
__global__ __launch_bounds__(512) void k_bscan(const int* __restrict__ gcnt,
                                               int* __restrict__ gbase, int nb) {
  __shared__ int sm[512];
  int t = threadIdx.x;
  int c = (t < nb) ? gcnt[t] : 0;
  int pc = (c + 15) & ~15;
  sm[t] = pc;
  __syncthreads();
  for (int off = 1; off < 512; off <<= 1) {
    int x = (t >= off) ? sm[t - off] : 0;
    __syncthreads();
    sm[t] += x;
    __syncthreads();
  }
  if (t < nb) gbase[t] = sm[t] - pc;
}

// ============ K3: scatter (blocks < NBLK)  ||  gemm tiles [tsplit, ntiles) ======
__global__ __launch_bounds__(512) void k_scatter_gemm(const int* __restrict__ ei,
                                                      const int* __restrict__ gbase,
                                                      const int* __restrict__ off_t,
                                                      int* __restrict__ binned,
                                                      int E, int nb,
                                                      const float* __restrict__ x,
                                                      const float* __restrict__ W,
                                                      __half* __restrict__ h1u,
                                                      int N, int tsplit, int ntiles) {
  __shared__ int cur[MAXNB];
  if (blockIdx.x < NBLK) {
    for (int b = threadIdx.x; b < nb; b += 512)
      cur[b] = gbase[b] + off_t[(size_t)b * NBLK + blockIdx.x];
    __syncthreads();
    int chunk = (E + NBLK - 1) / NBLK;
    int beg = blockIdx.x * chunk;
    int end = beg + chunk; if (end > E) end = E;
    for (int e = beg + threadIdx.x; e < end; e += 512) {
      int s = ei[e];
      int d = ei[(size_t)E + e];
      int b = d >> 8;
      int pos = atomicAdd(&cur[b], 1);
      binned[pos] = s | ((d & 255) << PACK_SHIFT);
    }
  } else {
    int tile = tsplit + (blockIdx.x - NBLK) * 8 + (threadIdx.x >> 6);
    if (tile < ntiles) gemm_tile(x, W, h1u, tile, N, threadIdx.x & 63);
  }
}

// ====== per-bucket sort -> CSR + dinv + h1 rescale (512 thr, dual hist) ======
__global__ __launch_bounds__(512) void k_sortbucket(const int* __restrict__ gbase,
                                                    const int* __restrict__ gcnt,
                                                    const int* __restrict__ binned,
                                                    int* __restrict__ csr,
                                                    int* __restrict__ rowbeg,
                                                    int* __restrict__ rowend,
                                                    float* __restrict__ dinv,
                                                    __half* __restrict__ h1h, int N) {
  __shared__ int hist[2][256];
  __shared__ int sm[256];
  __shared__ int cur[256];
  __shared__ float sdinv[256];
  const int t = threadIdx.x;
  const int b = blockIdx.x;
  const int base = gbase[b], cnt = gcnt[b];
  if (t < 256) {
    hist[0][t] = 0;
    hist[1][t] = 0;
  }
  __syncthreads();
  const int par = t & 1;
  for (int j = base + t; j < base + cnt; j += 512)
    atomicAdd(&hist[par][binned[j] >> PACK_SHIFT], 1);
  __syncthreads();
  int h = 0;
  if (t < 256) {
    h = hist[0][t] + hist[1][t];
    sm[t] = h;
  }
  __syncthreads();
  for (int off = 1; off < 256; off <<= 1) {
    int x = 0;
    if (t < 256 && t >= off) x = sm[t - off];
    __syncthreads();
    if (t < 256) sm[t] += x;
    __syncthreads();
  }
  if (t < 256) {
    int incl = sm[t];
    int excl = incl - h;
    cur[t] = excl;
    float dv = rsqrtf((float)h + 1.0f);
    sdinv[t] = dv;
    int node = b * 256 + t;
    if (node < N) {
      rowbeg[node] = base + excl;
      rowend[node] = base + incl;
      dinv[node] = dv;
    }
  }
  __syncthreads();
  for (int j = base + t; j < base + cnt; j += 512) {
    int val = binned[j];
    int pos = atomicAdd(&cur[val >> PACK_SHIFT], 1);
    csr[base + pos] = val & PACK_MASK;
  }
  // rescale h1u -> h1h in place: thread t handles half a row (8 fp16)
  {
    int node = b * 256 + (t >> 1);
    if (node < N) {
      float dv = sdinv[t >> 1];
      __half* hp = h1h + (size_t)node * HID + (t & 1) * 8;
      f16x8 v = *(const f16x8*)hp;
#pragma unroll
      for (int j = 0; j < 8; ++j) v[j] = (_Float16)((float)v[j] * dv);
      *(f16x8*)hp = v;
    }
  }
}

// ===== layer1 aggregation + relu + W2, fused. 16 lanes per node, fp16 h1. =====
__global__ __launch_bounds__(256) void k_agg1f(const int* __restrict__ rowbeg,
                                               const int* __restrict__ rowend,
                                               const int* __restrict__ csr,
                                               const __half* __restrict__ h1h,
                                               const float* __restrict__ dinv,
                                               const float* __restrict__ b1,
                                               const float* __restrict__ W2,
                                               float* __restrict__ h2s, int N) {
  const int f = threadIdx.x & 15;
  const int node = blockIdx.x * 16 + (threadIdx.x >> 4);
  if (node >= N) return;
  int j = rowbeg[node];
  const int end = rowend[node];
  float acc = __half2float(h1h[(size_t)node * HID + f]);  // self loop (pre-scaled)
  for (; j < end && (j & 3); ++j) acc += __half2float(h1h[(size_t)csr[j] * HID + f]);
  for (; j + 8 <= end; j += 8) {
    int4 s0 = *(const int4*)&csr[j];
    int4 s1 = *(const int4*)&csr[j + 4];
    float a0 = __half2float(h1h[(size_t)s0.x * HID + f]);
    float a1 = __half2float(h1h[(size_t)s0.y * HID + f]);
    float a2 = __half2float(h1h[(size_t)s0.z * HID + f]);
    float a3 = __half2float(h1h[(size_t)s0.w * HID + f]);
    float a4 = __half2float(h1h[(size_t)s1.x * HID + f]);
    float a5 = __half2float(h1h[(size_t)s1.y * HID + f]);
    float a6 = __half2float(h1h[(size_t)s1.z * HID + f]);
    float a7 = __half2float(h1h[(size_t)s1.w * HID + f]);
    acc += ((a0 + a1) + (a2 + a3)) + ((a4 + a5) + (a6 + a7));
  }
  for (; j + 4 <= end; j += 4) {
    int4 ss = *(const int4*)&csr[j];
    float a0 = __half2float(h1h[(size_t)ss.x * HID + f]);
    float a1 = __half2float(h1h[(size_t)ss.y * HID + f]);
    float a2 = __half2float(h1h[(size_t)ss.z * HID + f]);
    float a3 = __half2float(h1h[(size_t)ss.w * HID + f]);
    acc += (a0 + a1) + (a2 + a3);
  }
  for (; j < end; ++j) acc += __half2float(h1h[(size_t)csr[j] * HID + f]);

  float di = dinv[node];
  float v = fmaxf(acc * di + b1[f], 0.f);
  float o0 = v * W2[f * 2 + 0];
  float o1 = v * W2[f * 2 + 1];
#pragma unroll
  for (int d = 1; d < 16; d <<= 1) {
    o0 += __shfl_xor(o0, d);
    o1 += __shfl_xor(o1, d);
  }
  if (f == 0) *(float2*)&h2s[(size_t)node * 2] = make_float2(o0 * di, o1 * di);
}

// ===== layer2 aggregation + bias. 4 lanes per node (24 waves/CU). =====
__global__ __launch_bounds__(256) void k_agg2f(const int* __restrict__ rowbeg,
                                               const int* __restrict__ rowend,
                                               const int* __restrict__ csr,
                                               const float* __restrict__ h2s,
                                               const float* __restrict__ dinv,
                                               const float* __restrict__ b2,
                                               float* __restrict__ out, int N) {
  const int l = threadIdx.x & 3;
  const int node = blockIdx.x * 64 + (threadIdx.x >> 2);
  if (node >= N) return;
  const int beg = rowbeg[node];
  const int end = rowend[node];
  float ox = 0.f, oy = 0.f;
  for (int j = beg + l; j < end; j += 4) {
    int s = csr[j];
    float2 v = *(const float2*)&h2s[(size_t)s * 2];
    ox += v.x;
    oy += v.y;
  }
  ox += __shfl_xor(ox, 1); oy += __shfl_xor(oy, 1);
  ox += __shfl_xor(ox, 2); oy += __shfl_xor(oy, 2);
  if (l == 0) {
    float2 self = *(const float2*)&h2s[(size_t)node * 2];
    float di = dinv[node];
    float2 o;
    o.x = (ox + self.x) * di + b2[0];
    o.y = (oy + self.y) * di + b2[1];
    *(float2*)&out[(size_t)node * 2] = o;
  }
}

// ================= launch =================
extern "C" void kernel_launch(void* const* d_in, const int* in_sizes, int n_in,
                              void* d_out, int out_size, void* d_ws, size_t ws_size,
                              hipStream_t stream) {
  const float* x = (const float*)d_in[0];
  const int* ei = (const int*)d_in[1];  // harness delivers integer inputs as int32
  const float* W1 = (const float*)d_in[2];
  const float* b1 = (const float*)d_in[3];
  const float* W2 = (const float*)d_in[4];
  const float* b2 = (const float*)d_in[5];
  float* out = (float*)d_out;
  const int N = in_sizes[0] / NFEAT;
  const int E = in_sizes[1] / 2;
  const int nb = (N + 255) / 256;  // buckets of 256 nodes

  char* p = (char*)d_ws;
  int* cnt_t = (int*)p;    p += (size_t)MAXNB * NBLK * 4;
  int* off_t = (int*)p;    p += (size_t)MAXNB * NBLK * 4;
  int* gcnt = (int*)p;     p += (size_t)MAXNB * 4;
  int* gbase = (int*)p;    p += (size_t)MAXNB * 4;
  int* binned = (int*)p;   p += ((size_t)E + MAXNB * 16) * 4;
  int* csr = (int*)p;      p += ((size_t)E + MAXNB * 16) * 4;
  int* rowbeg = (int*)p;   p += (size_t)N * 4;
  int* rowend = (int*)p;   p += (size_t)N * 4;
  float* dinv = (float*)p; p += (size_t)N * 4;
  __half* h1h = (__half*)p; p += (size_t)N * HID * 2;
  float* h2s = (float*)p;  p += (size_t)N * 2 * 4;

  const int ntiles = (N + 15) / 16;
  const int tsplit = ((ntiles / 2) + 7) & ~7;           // first-half tiles, x8 aligned
  const int gA = (tsplit + 7) / 8;                       // gemm blocks in K1
  const int gB = (ntiles - tsplit + 7) / 8;              // gemm blocks in K3

  k_hist_gemm<<<NBLK + gA, 512, 0, stream>>>(ei, cnt_t, E, nb, x, W1, h1h, N, tsplit);
  k_colscan<<<nb, 64, 0, stream>>>(cnt_t, off_t, gcnt, nb);
  k_bscan<<<1, 512, 0, stream>>>(gcnt, gbase, nb);
  k_scatter_gemm<<<NBLK + gB, 512, 0, stream>>>(ei, gbase, off_t, binned, E, nb,
                                                x, W1, h1h, N, tsplit, ntiles);
  k_sortbucket<<<nb, 512, 0, stream>>>(gbase, gcnt, binned, csr, rowbeg, rowend,
                                       dinv, h1h, N);
  k_agg1f<<<(N + 15) / 16, 256, 0, stream>>>(rowbeg, rowend, csr, h1h, dinv, b1, W2, h2s, N);
  k_agg2f<<<(N + 63) / 64, 256, 0, stream>>>(rowbeg, rowend, csr, h2s, dinv, b2, out, N);
}

// Round 20
// 159.929 us; speedup vs baseline: 1.1424x; 1.0399x over previous
//
#include <hip/hip_runtime.h>
#include <hip/hip_fp16.h>

#define NFEAT 512
#define HID 16
#define MAXNB 512          // max buckets (N/256 = 391 for N=100K)
#define NBLK 512           // hist/scatter blocks within merged kernels
#define PACK_SHIFT 17      // src fits in 17 bits (N < 131072)
#define PACK_MASK ((1 << PACK_SHIFT) - 1)

typedef _Float16 f16x8 __attribute__((ext_vector_type(8)));
typedef float f32x4 __attribute__((ext_vector_type(4)));

// ---- shared device helper: one 16x16 MFMA tile of x@W1 (unscaled, fp16 out) ----
__device__ __forceinline__ void gemm_tile(const float* __restrict__ x,
                                          const float* __restrict__ W,
                                          __half* __restrict__ h1u,
                                          int tile, int N, int lane) {
  const int n = lane & 15;
  const int g = lane >> 4;

  f16x8 bf[16];
#pragma unroll
  for (int f = 0; f < 16; ++f) {
    const float* wp = W + (size_t)(f * 32 + g * 8) * HID + n;
#pragma unroll
    for (int j = 0; j < 8; ++j) bf[f][j] = (_Float16)wp[j * HID];
  }

  int rowbase = tile * 16;
  if (rowbase + 16 > N) rowbase = N - 16;  // overlap-safe: rewrites same values
  const float* xr = x + (size_t)(rowbase + n) * NFEAT + g * 8;

  f32x4 acc = {0.f, 0.f, 0.f, 0.f};
#pragma unroll
  for (int f = 0; f < 16; ++f) {
    float4 p0 = *(const float4*)(xr + f * 32);
    float4 p1 = *(const float4*)(xr + f * 32 + 4);
    f16x8 af;
    af[0] = (_Float16)p0.x; af[1] = (_Float16)p0.y;
    af[2] = (_Float16)p0.z; af[3] = (_Float16)p0.w;
    af[4] = (_Float16)p1.x; af[5] = (_Float16)p1.y;
    af[6] = (_Float16)p1.z; af[7] = (_Float16)p1.w;
    acc = __builtin_amdgcn_mfma_f32_16x16x32_f16(af, bf[f], acc, 0, 0, 0);
  }

#pragma unroll
  for (int r = 0; r < 4; ++r) {
    int row = rowbase + g * 4 + r;
    h1u[(size_t)row * HID + n] = __float2half(acc[r]);
  }
}

// ==== K1: hist2d (blocks < NBLK) || gemm tiles [0, tsplit) ====
__global__ __launch_bounds__(512) void k_hist_gemm(const int* __restrict__ ei,
                                                   int* __restrict__ cnt_t,
                                                   int E, int nb,
                                                   const float* __restrict__ x,
                                                   const float* __restrict__ W,
                                                   __half* __restrict__ h1u,
                                                   int N, int tsplit) {
  __shared__ int l[MAXNB];
  if (blockIdx.x < NBLK) {
    for (int i = threadIdx.x; i < nb; i += 512) l[i] = 0;
    __syncthreads();
    int chunk = (E + NBLK - 1) / NBLK;
    int beg = blockIdx.x * chunk;
    int end = beg + chunk; if (end > E) end = E;
    for (int e = beg + threadIdx.x; e < end; e += 512)
      atomicAdd(&l[ei[(size_t)E + e] >> 8], 1);
    __syncthreads();
    for (int b = threadIdx.x; b < nb; b += 512)
      cnt_t[(size_t)b * NBLK + blockIdx.x] = l[b];
  } else {
    int tile = (blockIdx.x - NBLK) * 8 + (threadIdx.x >> 6);
    if (tile < tsplit) gemm_tile(x, W, h1u, tile, N, threadIdx.x & 63);
  }
}

// ============ per-bucket column scan (one wave per bucket, 8 counts/lane) ====
__global__ __launch_bounds__(64) void k_colscan(const int* __restrict__ cnt_t,
                                                int* __restrict__ off_t,
                                                int* __restrict__ gcnt, int nb) {
  int b = blockIdx.x;
  if (b >= nb) return;
  int lane = threadIdx.x;
  int4 v0 = *(const int4*)&cnt_t[(size_t)b * NBLK + lane * 8];
  int4 v1 = *(const int4*)&cnt_t[(size_t)b * NBLK + lane * 8 + 4];
  int tot = (v0.x + v0.y + v0.z + v0.w) + (v1.x + v1.y + v1.z + v1.w);
  int s = tot;
  for (int d = 1; d < 64; d <<= 1) {
    int o = __shfl_up(s, d);
    if (lane >= d) s += o;
  }
  int excl = s - tot;
  int4 w0, w1;
  w0.x = excl;
  w0.y = w0.x + v0.x;
  w0.z = w0.y + v0.y;
  w0.w = w0.z + v0.z;
  w1.x = w0.w + v0.w;
  w1.y = w1.x + v1.x;
  w1.z = w1.y + v1.y;
  w1.w = w1.z + v1.z;
  *(int4*)&off_t[(size_t)b * NBLK + lane * 8] = w0;
  *(int4*)&off_t[(size_t)b * NBLK + lane * 8 + 4] = w1;
  if (lane == 63) gcnt[b] = s;
}

// ============ scan: 16-aligned bucket bases ============
__global__ __launch_bounds__(512) void k_bscan(const int* __restrict__ gcnt,
                                               int* __restrict__ gbase, int nb) {
  __shared__ int sm[512];
  int t = threadIdx.x;
  int c = (t < nb) ? gcnt[t] : 0;
  int pc = (c + 15) & ~15;
  sm[t] = pc;
  __syncthreads();
  for (int off = 1; off < 512; off <<= 1) {
    int x = (t >= off) ? sm[t - off] : 0;
    __syncthreads();
    sm[t] += x;
    __syncthreads();
  }
  if (t < nb) gbase[t] = sm[t] - pc;
}

// ============ K3: scatter (blocks < NBLK)  ||  gemm tiles [tsplit, ntiles) ======
__global__ __launch_bounds__(512) void k_scatter_gemm(const int* __restrict__ ei,
                                                      const int* __restrict__ gbase,
                                                      const int* __restrict__ off_t,
                                                      int* __restrict__ binned,
                                                      int E, int nb,
                                                      const float* __restrict__ x,
                                                      const float* __restrict__ W,
                                                      __half* __restrict__ h1u,
                                                      int N, int tsplit, int ntiles) {
  __shared__ int cur[MAXNB];
  if (blockIdx.x < NBLK) {
    for (int b = threadIdx.x; b < nb; b += 512)
      cur[b] = gbase[b] + off_t[(size_t)b * NBLK + blockIdx.x];
    __syncthreads();
    int chunk = (E + NBLK - 1) / NBLK;
    int beg = blockIdx.x * chunk;
    int end = beg + chunk; if (end > E) end = E;
    for (int e = beg + threadIdx.x; e < end; e += 512) {
      int s = ei[e];
      int d = ei[(size_t)E + e];
      int b = d >> 8;
      int pos = atomicAdd(&cur[b], 1);
      binned[pos] = s | ((d & 255) << PACK_SHIFT);
    }
  } else {
    int tile = tsplit + (blockIdx.x - NBLK) * 8 + (threadIdx.x >> 6);
    if (tile < ntiles) gemm_tile(x, W, h1u, tile, N, threadIdx.x & 63);
  }
}

// ====== per-bucket sort -> CSR + dinv + h1 rescale (1024 thr, 24 waves/CU) ======
__global__ __launch_bounds__(1024) void k_sortbucket(const int* __restrict__ gbase,
                                                     const int* __restrict__ gcnt,
                                                     const int* __restrict__ binned,
                                                     int* __restrict__ csr,
                                                     int* __restrict__ rowbeg,
                                                     int* __restrict__ rowend,
                                                     float* __restrict__ dinv,
                                                     __half* __restrict__ h1h, int N) {
  __shared__ int hist[256];
  __shared__ int sm[256];
  __shared__ int cur[256];
  __shared__ float sdinv[256];
  const int t = threadIdx.x;
  const int b = blockIdx.x;
  const int base = gbase[b], cnt = gcnt[b];
  if (t < 256) hist[t] = 0;
  __syncthreads();
  for (int j = base + t; j < base + cnt; j += 1024)
    atomicAdd(&hist[binned[j] >> PACK_SHIFT], 1);
  __syncthreads();
  int h = 0;
  if (t < 256) {
    h = hist[t];
    sm[t] = h;
  }
  __syncthreads();
  for (int off = 1; off < 256; off <<= 1) {
    int x = 0;
    if (t < 256 && t >= off) x = sm[t - off];
    __syncthreads();
    if (t < 256) sm[t] += x;
    __syncthreads();
  }
  if (t < 256) {
    int incl = sm[t];
    int excl = incl - h;
    cur[t] = excl;
    float dv = rsqrtf((float)h + 1.0f);
    sdinv[t] = dv;
    int node = b * 256 + t;
    if (node < N) {
      rowbeg[node] = base + excl;
      rowend[node] = base + incl;
      dinv[node] = dv;
    }
  }
  __syncthreads();
  for (int j = base + t; j < base + cnt; j += 1024) {
    int val = binned[j];
    int pos = atomicAdd(&cur[val >> PACK_SHIFT], 1);
    csr[base + pos] = val & PACK_MASK;
  }
  // rescale h1u -> h1h in place: threads 0..511 handle half-rows (8 fp16 each)
  if (t < 512) {
    int node = b * 256 + (t >> 1);
    if (node < N) {
      float dv = sdinv[t >> 1];
      __half* hp = h1h + (size_t)node * HID + (t & 1) * 8;
      f16x8 v = *(const f16x8*)hp;
#pragma unroll
      for (int j = 0; j < 8; ++j) v[j] = (_Float16)((float)v[j] * dv);
      *(f16x8*)hp = v;
    }
  }
}

// ===== layer1 agg + relu + W2. 8 lanes/node, __half2 gathers (half the loads). =====
__global__ __launch_bounds__(256) void k_agg1f(const int* __restrict__ rowbeg,
                                               const int* __restrict__ rowend,
                                               const int* __restrict__ csr,
                                               const __half* __restrict__ h1h,
                                               const float* __restrict__ dinv,
                                               const float* __restrict__ b1,
                                               const float* __restrict__ W2,
                                               float* __restrict__ h2s, int N) {
  const int l = threadIdx.x & 7;                       // feature-pair lane
  const int node = blockIdx.x * 32 + (threadIdx.x >> 3);
  if (node >= N) return;
  const __half2* hp = (const __half2*)h1h;             // row stride = 8 half2
  int j = rowbeg[node];
  const int end = rowend[node];
  float2 a = __half22float2(hp[(size_t)node * 8 + l]);  // self loop (pre-scaled)
  float accx = a.x, accy = a.y;
  for (; j < end && (j & 3); ++j) {
    float2 v = __half22float2(hp[(size_t)csr[j] * 8 + l]);
    accx += v.x; accy += v.y;
  }
  for (; j + 8 <= end; j += 8) {
    int4 s0 = *(const int4*)&csr[j];
    int4 s1 = *(const int4*)&csr[j + 4];
    float2 v0 = __half22float2(hp[(size_t)s0.x * 8 + l]);
    float2 v1 = __half22float2(hp[(size_t)s0.y * 8 + l]);
    float2 v2 = __half22float2(hp[(size_t)s0.z * 8 + l]);
    float2 v3 = __half22float2(hp[(size_t)s0.w * 8 + l]);
    float2 v4 = __half22float2(hp[(size_t)s1.x * 8 + l]);
    float2 v5 = __half22float2(hp[(size_t)s1.y * 8 + l]);
    float2 v6 = __half22float2(hp[(size_t)s1.z * 8 + l]);
    float2 v7 = __half22float2(hp[(size_t)s1.w * 8 + l]);
    accx += ((v0.x + v1.x) + (v2.x + v3.x)) + ((v4.x + v5.x) + (v6.x + v7.x));
    accy += ((v0.y + v1.y) + (v2.y + v3.y)) + ((v4.y + v5.y) + (v6.y + v7.y));
  }
  for (; j + 4 <= end; j += 4) {
    int4 ss = *(const int4*)&csr[j];
    float2 v0 = __half22float2(hp[(size_t)ss.x * 8 + l]);
    float2 v1 = __half22float2(hp[(size_t)ss.y * 8 + l]);
    float2 v2 = __half22float2(hp[(size_t)ss.z * 8 + l]);
    float2 v3 = __half22float2(hp[(size_t)ss.w * 8 + l]);
    accx += (v0.x + v1.x) + (v2.x + v3.x);
    accy += (v0.y + v1.y) + (v2.y + v3.y);
  }
  for (; j < end; ++j) {
    float2 v = __half22float2(hp[(size_t)csr[j] * 8 + l]);
    accx += v.x; accy += v.y;
  }

  const float di = dinv[node];
  const int f0 = 2 * l;
  float w0 = fmaxf(accx * di + b1[f0], 0.f);
  float w1 = fmaxf(accy * di + b1[f0 + 1], 0.f);
  float o0 = w0 * W2[f0 * 2 + 0] + w1 * W2[(f0 + 1) * 2 + 0];
  float o1 = w0 * W2[f0 * 2 + 1] + w1 * W2[(f0 + 1) * 2 + 1];
#pragma unroll
  for (int d = 1; d < 8; d <<= 1) {
    o0 += __shfl_xor(o0, d);
    o1 += __shfl_xor(o1, d);
  }
  if (l == 0) *(float2*)&h2s[(size_t)node * 2] = make_float2(o0 * di, o1 * di);
}

// ===== layer2 aggregation + bias. 4 lanes per node (24 waves/CU). =====
__global__ __launch_bounds__(256) void k_agg2f(const int* __restrict__ rowbeg,
                                               const int* __restrict__ rowend,
                                               const int* __restrict__ csr,
                                               const float* __restrict__ h2s,
                                               const float* __restrict__ dinv,
                                               const float* __restrict__ b2,
                                               float* __restrict__ out, int N) {
  const int l = threadIdx.x & 3;
  const int node = blockIdx.x * 64 + (threadIdx.x >> 2);
  if (node >= N) return;
  const int beg = rowbeg[node];
  const int end = rowend[node];
  float ox = 0.f, oy = 0.f;
  for (int j = beg + l; j < end; j += 4) {
    int s = csr[j];
    float2 v = *(const float2*)&h2s[(size_t)s * 2];
    ox += v.x;
    oy += v.y;
  }
  ox += __shfl_xor(ox, 1); oy += __shfl_xor(oy, 1);
  ox += __shfl_xor(ox, 2); oy += __shfl_xor(oy, 2);
  if (l == 0) {
    float2 self = *(const float2*)&h2s[(size_t)node * 2];
    float di = dinv[node];
    float2 o;
    o.x = (ox + self.x) * di + b2[0];
    o.y = (oy + self.y) * di + b2[1];
    *(float2*)&out[(size_t)node * 2] = o;
  }
}

// ================= launch =================
extern "C" void kernel_launch(void* const* d_in, const int* in_sizes, int n_in,
                              void* d_out, int out_size, void* d_ws, size_t ws_size,
                              hipStream_t stream) {
  const float* x = (const float*)d_in[0];
  const int* ei = (const int*)d_in[1];  // harness delivers integer inputs as int32
  const float* W1 = (const float*)d_in[2];
  const float* b1 = (const float*)d_in[3];
  const float* W2 = (const float*)d_in[4];
  const float* b2 = (const float*)d_in[5];
  float* out = (float*)d_out;
  const int N = in_sizes[0] / NFEAT;
  const int E = in_sizes[1] / 2;
  const int nb = (N + 255) / 256;  // buckets of 256 nodes

  char* p = (char*)d_ws;
  int* cnt_t = (int*)p;    p += (size_t)MAXNB * NBLK * 4;
  int* off_t = (int*)p;    p += (size_t)MAXNB * NBLK * 4;
  int* gcnt = (int*)p;     p += (size_t)MAXNB * 4;
  int* gbase = (int*)p;    p += (size_t)MAXNB * 4;
  int* binned = (int*)p;   p += ((size_t)E + MAXNB * 16) * 4;
  int* csr = (int*)p;      p += ((size_t)E + MAXNB * 16) * 4;
  int* rowbeg = (int*)p;   p += (size_t)N * 4;
  int* rowend = (int*)p;   p += (size_t)N * 4;
  float* dinv = (float*)p; p += (size_t)N * 4;
  __half* h1h = (__half*)p; p += (size_t)N * HID * 2;
  float* h2s = (float*)p;  p += (size_t)N * 2 * 4;

  const int ntiles = (N + 15) / 16;
  const int tsplit = ((ntiles / 2) + 7) & ~7;           // first-half tiles, x8 aligned
  const int gA = (tsplit + 7) / 8;                       // gemm blocks in K1
  const int gB = (ntiles - tsplit + 7) / 8;              // gemm blocks in K3

  k_hist_gemm<<<NBLK + gA, 512, 0, stream>>>(ei, cnt_t, E, nb, x, W1, h1h, N, tsplit);
  k_colscan<<<nb, 64, 0, stream>>>(cnt_t, off_t, gcnt, nb);
  k_bscan<<<1, 512, 0, stream>>>(gcnt, gbase, nb);
  k_scatter_gemm<<<NBLK + gB, 512, 0, stream>>>(ei, gbase, off_t, binned, E, nb,
                                                x, W1, h1h, N, tsplit, ntiles);
  k_sortbucket<<<nb, 1024, 0, stream>>>(gbase, gcnt, binned, csr, rowbeg, rowend,
                                        dinv, h1h, N);
  k_agg1f<<<(N + 31) / 32, 256, 0, stream>>>(rowbeg, rowend, csr, h1h, dinv, b1, W2, h2s, N);
  k_agg2f<<<(N + 63) / 64, 256, 0, stream>>>(rowbeg, rowend, csr, h2s, dinv, b2, out, N);
}